// Round 8
// baseline (445.014 us; speedup 1.0000x reference)
//
#include <hip/hip_runtime.h>

// ---------------------------------------------------------------------------
// RNN-T Joint Network, MI355X (gfx950)
//   f  = enc  @ W_enc^T   : [2048 x 640]
//   g  = pred @ W_pred^T  : [ 512 x 640]
//   out[b,t,u,v] = sum_j tanh(f[bt,j] + g[bu,j]) * W_out[v,j] + b_out[v]
// R8: conflict-free LDS layouts derived by enumeration (B col-chunk-major
// via gll source scatter -> identity ds_read; A padded col-chunk-major,
// 1088B chunk regions -> zero-conflict read AND write), and f/g loads
// issued BEFORE glls (tanh's vmcnt wait no longer drains the gll queue).
// Structure otherwise = R6: BM=64, BN=512, BK=32, 4 waves, 2 blocks/CU.
// ---------------------------------------------------------------------------

typedef _Float16 f16x8 __attribute__((ext_vector_type(8)));
typedef float    f32x4 __attribute__((ext_vector_type(4)));

__device__ __forceinline__ float fast_tanh(float x) {
    float e = __builtin_amdgcn_exp2f(x * 2.88539008177792681472f);
    return 1.0f - 2.0f * __builtin_amdgcn_rcpf(e + 1.0f);
}

__device__ __forceinline__ void gll16(const void* g, void* l) {
    __builtin_amdgcn_global_load_lds(
        (const __attribute__((address_space(1))) void*)g,
        (__attribute__((address_space(3))) void*)l, 16, 0, 0);
}

// ---------------------------------------------------------------------------
// Kernel 1: fg GEMM (fp32, exact). W staged transposed -> broadcast reads.
// ---------------------------------------------------------------------------
__global__ __launch_bounds__(256) void fg_kernel(
    const float* __restrict__ enc, const float* __restrict__ pred,
    const float* __restrict__ Wenc, const float* __restrict__ Wpred,
    float* __restrict__ fg)
{
    __shared__ float As[64][36];
    __shared__ float WsT[32][68];

    const int bid = blockIdx.x;
    const int mt = bid / 10;
    const int nt = bid % 10;
    const int m0 = mt * 64;
    const int n0 = nt * 64;

    const float* Aptr;
    const float* Wptr;
    if (m0 < 2048) { Aptr = enc  + (size_t)m0 * 512;          Wptr = Wenc; }
    else           { Aptr = pred + (size_t)(m0 - 2048) * 512; Wptr = Wpred; }

    const int t  = threadIdx.x;
    const int ty = t >> 4;
    const int tx = t & 15;
    const int lr = t >> 2;
    const int lc = (t & 3) * 8;
    const int lane6 = t & 63;
    const int w8    = (t >> 6) * 8;

    float acc[4][4];
#pragma unroll
    for (int i = 0; i < 4; ++i)
#pragma unroll
        for (int j = 0; j < 4; ++j) acc[i][j] = 0.0f;

    for (int k0 = 0; k0 < 512; k0 += 32) {
        __syncthreads();
        {
            const float* sa = Aptr + (size_t)lr * 512 + k0 + lc;
            f32x4 a0 = *(const f32x4*)(sa);
            f32x4 a1 = *(const f32x4*)(sa + 4);
            *(f32x4*)&As[lr][lc]     = a0;
            *(f32x4*)&As[lr][lc + 4] = a1;
            const float* sw = Wptr + (size_t)(n0 + lane6) * 512 + k0 + w8;
            f32x4 w0 = *(const f32x4*)(sw);
            f32x4 w1 = *(const f32x4*)(sw + 4);
#pragma unroll
            for (int j = 0; j < 4; ++j) {
                WsT[w8 + j][lane6]     = w0[j];
                WsT[w8 + 4 + j][lane6] = w1[j];
            }
        }
        __syncthreads();
#pragma unroll
        for (int kk = 0; kk < 32; ++kk) {
            float av[4], bv[4];
#pragma unroll
            for (int i = 0; i < 4; ++i) av[i] = As[ty * 4 + i][kk];
#pragma unroll
            for (int j = 0; j < 4; ++j) bv[j] = WsT[kk][tx * 4 + j];
#pragma unroll
            for (int i = 0; i < 4; ++i)
#pragma unroll
                for (int j = 0; j < 4; ++j)
                    acc[i][j] = fmaf(av[i], bv[j], acc[i][j]);
        }
    }

#pragma unroll
    for (int i = 0; i < 4; ++i) {
        f32x4 v = { acc[i][0], acc[i][1], acc[i][2], acc[i][3] };
        *(f32x4*)&fg[(size_t)(m0 + ty * 4 + i) * 640 + n0 + tx * 4] = v;
    }
}

// ---------------------------------------------------------------------------
// Kernel 2: W_out fp32 [1024][640] -> fp16 same layout.
// ---------------------------------------------------------------------------
__global__ __launch_bounds__(256) void wconv_kernel(
    const float* __restrict__ W, _Float16* __restrict__ Wh)
{
    const int idx = (blockIdx.x * 256 + threadIdx.x) * 8;
    f32x4 a = *(const f32x4*)(W + idx);
    f32x4 b = *(const f32x4*)(W + idx + 4);
    f16x8 h;
#pragma unroll
    for (int j = 0; j < 4; ++j) { h[j] = (_Float16)a[j]; h[4 + j] = (_Float16)b[j]; }
    *(f16x8*)(Wh + idx) = h;
}

// ---------------------------------------------------------------------------
// Kernel 3: fused tanh + big GEMM.  BM=64, BN=512, BK=32, 256 thr = 4 waves,
// wave tile 64m x 128n (4x8 frags, 128 AGPR). 2 blocks/CU.
//
// LDS layouts (enumerated conflict-free for b128 at 8-lane-group granularity):
//  B: col-chunk-major per 16-row segment: slot L = row + 16*chunk; gll writes
//     lane L at seg_base + L*16 (linear, HW), source scattered so slot L
//     holds (row=L&15, chunk=L>>4). Read lane l = seg_base + l*16 (identity).
//  A: chunk region c at byte c*1088 (68 slots pad), row r at +r*16.
//     quad = (4c + r) % 8 -> distinct in every 8-lane group for write
//     (r=t>>2, c=t&3) and read (r=mf*16+lr, c=lk).
// Per-iter: f/g loads FIRST, then glls (tanh waits vmcnt(8), glls fly on),
// frag reads, tanh->regs, MFMA, ds_write A, __syncthreads.
// ---------------------------------------------------------------------------
__global__ __launch_bounds__(256, 2) void joint_kernel(
    const float* __restrict__ fg, const _Float16* __restrict__ Wh,
    const float* __restrict__ bias, float* __restrict__ out)
{
    __shared__ _Float16 Ash0[4 * 544];     // 4352 B
    __shared__ _Float16 Ash1[4 * 544];
    __shared__ _Float16 Bsh0[512 * 32];    // 32 KB
    __shared__ _Float16 Bsh1[512 * 32];

    const int bid = blockIdx.x;            // 4096
    const int pp  = bid >> 1;              // 2048 m-tiles
    const int mt  = (pp & 7) * 256 + (pp >> 3);   // XCD-chunked (bijective)
    const int nt  = bid & 1;
    const int m0  = mt << 6;
    const int n0  = nt << 9;

    const int t    = threadIdx.x;
    const int lane = t & 63;
    const int wid  = t >> 6;               // = wn, 0..3 (128-col quarter)
    const int wn   = wid;
    const int lr   = lane & 15;
    const int lk   = lane >> 4;

    // stage-A mapping: 4 threads per row, 8 k each
    const int r  = t >> 2;                 // 0..63
    const int q  = t & 3;
    const int m  = m0 + r;
    const float* grow = fg + (size_t)(2048 + ((m >> 14) << 6) + (m & 63)) * 640;
    const float* frow = fg + (size_t)(m >> 6) * 640;   // same row, whole block

    // ---- loop-invariant LDS offsets (f16 elems) ----
    int aoff[4];
#pragma unroll
    for (int mf = 0; mf < 4; ++mf)
        aoff[mf] = lk * 544 + (mf * 16 + lr) * 8;      // A read: chunk lk, row
    int boff[8];
#pragma unroll
    for (int nf = 0; nf < 8; ++nf)
        boff[nf] = (wn * 8 + nf) * 512 + lane * 8;     // B read: identity
    const int awoff = q * 544 + r * 8;                 // A write: chunk q, row r

    // gll source scatter: lane L of segment seg reads W row seg*16+(L&15),
    // k-chunk L>>4  -> lands at LDS slot L = row + 16*chunk (col-chunk-major)
    const _Float16* gsrc[8];
    int gdst[8];
#pragma unroll
    for (int i = 0; i < 8; ++i) {
        const int seg = wid * 8 + i;
        gsrc[i] = Wh + (size_t)(n0 + seg * 16 + lr) * 640 + lk * 8;
        gdst[i] = seg * 512;
    }

    f32x4 acc[4][8];
#pragma unroll
    for (int i = 0; i < 4; ++i)
#pragma unroll
        for (int j = 0; j < 8; ++j) acc[i][j] = (f32x4){0.f, 0.f, 0.f, 0.f};

    // ---- prologue: stage k-range 0 into Ash0/Bsh0 ----
    {
        f32x4 fv0 = *(const f32x4*)(frow + q * 8);
        f32x4 fv1 = *(const f32x4*)(frow + q * 8 + 4);
        f32x4 gv0 = *(const f32x4*)(grow + q * 8);
        f32x4 gv1 = *(const f32x4*)(grow + q * 8 + 4);
#pragma unroll
        for (int i = 0; i < 8; ++i)
            gll16(gsrc[i], &Bsh0[gdst[i]]);
        f16x8 h;
#pragma unroll
        for (int j = 0; j < 4; ++j) {
            h[j]     = (_Float16)fast_tanh(fv0[j] + gv0[j]);
            h[4 + j] = (_Float16)fast_tanh(fv1[j] + gv1[j]);
        }
        *(f16x8*)&Ash0[awoff] = h;
        __syncthreads();
    }

#define JITER_FULL(K0, CA, CB, NA, NB)                                         \
    {                                                                          \
        const int kn_ = (K0) + 32;                                             \
        /* f/g loads FIRST (tanh's vmcnt wait won't drain glls) */             \
        f32x4 fv0_ = *(const f32x4*)(frow + kn_ + q * 8);                      \
        f32x4 fv1_ = *(const f32x4*)(frow + kn_ + q * 8 + 4);                  \
        f32x4 gv0_ = *(const f32x4*)(grow + kn_ + q * 8);                      \
        f32x4 gv1_ = *(const f32x4*)(grow + kn_ + q * 8 + 4);                  \
        _Pragma("unroll")                                                      \
        for (int i = 0; i < 8; ++i)                                            \
            gll16(gsrc[i] + kn_, &NB[gdst[i]]);                                \
        f16x8 af[4], bf[8];                                                    \
        _Pragma("unroll")                                                      \
        for (int mf = 0; mf < 4; ++mf)                                         \
            af[mf] = *(const f16x8*)&CA[aoff[mf]];                             \
        _Pragma("unroll")                                                      \
        for (int nf = 0; nf < 8; ++nf)                                         \
            bf[nf] = *(const f16x8*)&CB[boff[nf]];                             \
        f16x8 h_;                                                              \
        _Pragma("unroll")                                                      \
        for (int j = 0; j < 4; ++j) {                                          \
            h_[j]     = (_Float16)fast_tanh(fv0_[j] + gv0_[j]);                \
            h_[4 + j] = (_Float16)fast_tanh(fv1_[j] + gv1_[j]);                \
        }                                                                      \
        _Pragma("unroll")                                                      \
        for (int mf = 0; mf < 4; ++mf)                                         \
            _Pragma("unroll")                                                  \
            for (int nf = 0; nf < 8; ++nf)                                     \
                acc[mf][nf] = __builtin_amdgcn_mfma_f32_16x16x32_f16(          \
                    af[mf], bf[nf], acc[mf][nf], 0, 0, 0);                     \
        *(f16x8*)&NA[awoff] = h_;                                              \
        __syncthreads();                                                       \
    }

#define JITER_LAST(CA, CB)                                                     \
    {                                                                          \
        f16x8 af[4], bf[8];                                                    \
        _Pragma("unroll")                                                      \
        for (int mf = 0; mf < 4; ++mf)                                         \
            af[mf] = *(const f16x8*)&CA[aoff[mf]];                             \
        _Pragma("unroll")                                                      \
        for (int nf = 0; nf < 8; ++nf)                                         \
            bf[nf] = *(const f16x8*)&CB[boff[nf]];                             \
        _Pragma("unroll")                                                      \
        for (int mf = 0; mf < 4; ++mf)                                         \
            _Pragma("unroll")                                                  \
            for (int nf = 0; nf < 8; ++nf)                                     \
                acc[mf][nf] = __builtin_amdgcn_mfma_f32_16x16x32_f16(          \
                    af[mf], bf[nf], acc[mf][nf], 0, 0, 0);                     \
    }

    for (int kc = 0; kc < 18; kc += 2) {
        JITER_FULL(kc * 32,      Ash0, Bsh0, Ash1, Bsh1);
        JITER_FULL(kc * 32 + 32, Ash1, Bsh1, Ash0, Bsh0);
    }
    JITER_FULL(576, Ash0, Bsh0, Ash1, Bsh1);   // computes k=576, stages 608
    JITER_LAST(Ash1, Bsh1);                    // computes k=608

#undef JITER_FULL
#undef JITER_LAST

    // ---- epilogue: + bias, store fp32 ----
    float bv[8];
#pragma unroll
    for (int nf = 0; nf < 8; ++nf)
        bv[nf] = bias[n0 + wn * 128 + nf * 16 + lr];

#pragma unroll
    for (int mf = 0; mf < 4; ++mf) {
#pragma unroll
        for (int rr = 0; rr < 4; ++rr) {
            const int row = m0 + mf * 16 + lk * 4 + rr;
            float* orow = out + (size_t)row * 1024 + n0 + wn * 128;
#pragma unroll
            for (int nf = 0; nf < 8; ++nf)
                orow[nf * 16 + lr] = acc[mf][nf][rr] + bv[nf];
        }
    }
}

// ---------------------------------------------------------------------------
extern "C" void kernel_launch(void* const* d_in, const int* in_sizes, int n_in,
                              void* d_out, int out_size, void* d_ws, size_t ws_size,
                              hipStream_t stream) {
    const float* enc   = (const float*)d_in[0];   // [8,256,512]
    const float* pred  = (const float*)d_in[1];   // [8,64,512]
    const float* Wenc  = (const float*)d_in[2];   // [640,512]
    const float* Wpred = (const float*)d_in[3];   // [640,512]
    const float* Wout  = (const float*)d_in[4];   // [1024,640]
    const float* bout  = (const float*)d_in[5];   // [1024]

    float*     fg = (float*)d_ws;                              // 2560*640 fp32
    _Float16*  Wh = (_Float16*)((char*)d_ws + 2560 * 640 * 4); // 1024*640 fp16

    fg_kernel<<<400, 256, 0, stream>>>(enc, pred, Wenc, Wpred, fg);
    wconv_kernel<<<320, 256, 0, stream>>>(Wout, Wh);
    joint_kernel<<<4096, 256, 0, stream>>>(fg, Wh, bout, (float*)d_out);
}

// Round 9
// 285.647 us; speedup vs baseline: 1.5579x; 1.5579x over previous
//
#include <hip/hip_runtime.h>

// ---------------------------------------------------------------------------
// RNN-T Joint Network, MI355X (gfx950)
//   f  = enc  @ W_enc^T   : [2048 x 640]
//   g  = pred @ W_pred^T  : [ 512 x 640]
//   out[b,t,u,v] = sum_j tanh(f[bt,j] + g[bu,j]) * W_out[v,j] + b_out[v]
// R9 = R4 structure (BM=128, BN=512, BK=32, 512 thr = 8 waves, 1 block/CU)
//   + Wh PRE-TILED in global memory to the exact LDS image wanted:
//       Wh_t[seg][kc][L][8], seg=n>>4, kc=k>>5, L=(n&15)+16*((k>>3)&3)
//     -> gll reads are contiguous 1KB/wave (coalesced) AND ds_read is
//        identity lane*16 (zero bank conflict), no swizzle math at all.
//   + A layout with chunk-region stride 2080B (≡2 mod 8 bank-quads):
//        write quads (2q+r)%8 and read quads (2lk+r)%8 both distinct per
//        8-lane group -> zero conflicts on both sides (enumerated).
//   + f/g loads issued BEFORE glls (in-order vmcnt retire: tanh waits at
//     vmcnt(4), the 4 glls stay in flight until the barrier).
// ---------------------------------------------------------------------------

typedef _Float16 f16x8 __attribute__((ext_vector_type(8)));
typedef float    f32x4 __attribute__((ext_vector_type(4)));

__device__ __forceinline__ float fast_tanh(float x) {
    float e = __builtin_amdgcn_exp2f(x * 2.88539008177792681472f);
    return 1.0f - 2.0f * __builtin_amdgcn_rcpf(e + 1.0f);
}

__device__ __forceinline__ void gll16(const void* g, void* l) {
    __builtin_amdgcn_global_load_lds(
        (const __attribute__((address_space(1))) void*)g,
        (__attribute__((address_space(3))) void*)l, 16, 0, 0);
}

// ---------------------------------------------------------------------------
// Kernel 1: fg GEMM (fp32, exact). W staged transposed -> broadcast reads.
// ---------------------------------------------------------------------------
__global__ __launch_bounds__(256) void fg_kernel(
    const float* __restrict__ enc, const float* __restrict__ pred,
    const float* __restrict__ Wenc, const float* __restrict__ Wpred,
    float* __restrict__ fg)
{
    __shared__ float As[64][36];
    __shared__ float WsT[32][68];

    const int bid = blockIdx.x;
    const int mt = bid / 10;
    const int nt = bid % 10;
    const int m0 = mt * 64;
    const int n0 = nt * 64;

    const float* Aptr;
    const float* Wptr;
    if (m0 < 2048) { Aptr = enc  + (size_t)m0 * 512;          Wptr = Wenc; }
    else           { Aptr = pred + (size_t)(m0 - 2048) * 512; Wptr = Wpred; }

    const int t  = threadIdx.x;
    const int ty = t >> 4;
    const int tx = t & 15;
    const int lr = t >> 2;
    const int lc = (t & 3) * 8;
    const int lane6 = t & 63;
    const int w8    = (t >> 6) * 8;

    float acc[4][4];
#pragma unroll
    for (int i = 0; i < 4; ++i)
#pragma unroll
        for (int j = 0; j < 4; ++j) acc[i][j] = 0.0f;

    for (int k0 = 0; k0 < 512; k0 += 32) {
        __syncthreads();
        {
            const float* sa = Aptr + (size_t)lr * 512 + k0 + lc;
            f32x4 a0 = *(const f32x4*)(sa);
            f32x4 a1 = *(const f32x4*)(sa + 4);
            *(f32x4*)&As[lr][lc]     = a0;
            *(f32x4*)&As[lr][lc + 4] = a1;
            const float* sw = Wptr + (size_t)(n0 + lane6) * 512 + k0 + w8;
            f32x4 w0 = *(const f32x4*)(sw);
            f32x4 w1 = *(const f32x4*)(sw + 4);
#pragma unroll
            for (int j = 0; j < 4; ++j) {
                WsT[w8 + j][lane6]     = w0[j];
                WsT[w8 + 4 + j][lane6] = w1[j];
            }
        }
        __syncthreads();
#pragma unroll
        for (int kk = 0; kk < 32; ++kk) {
            float av[4], bv[4];
#pragma unroll
            for (int i = 0; i < 4; ++i) av[i] = As[ty * 4 + i][kk];
#pragma unroll
            for (int j = 0; j < 4; ++j) bv[j] = WsT[kk][tx * 4 + j];
#pragma unroll
            for (int i = 0; i < 4; ++i)
#pragma unroll
                for (int j = 0; j < 4; ++j)
                    acc[i][j] = fmaf(av[i], bv[j], acc[i][j]);
        }
    }

#pragma unroll
    for (int i = 0; i < 4; ++i) {
        f32x4 v = { acc[i][0], acc[i][1], acc[i][2], acc[i][3] };
        *(f32x4*)&fg[(size_t)(m0 + ty * 4 + i) * 640 + n0 + tx * 4] = v;
    }
}

// ---------------------------------------------------------------------------
// Kernel 2: W_out fp32 [1024][640] -> fp16, TILED to the joint kernel's LDS
// image: elem offset = seg*10240 + kc*512 + L*8 + j, where seg = n>>4,
// kc = k>>5, L = (n&15) + 16*((k>>3)&3).  Then a 64-lane gll at
// base + lane*8 reads one contiguous 1KB tile whose slot L holds exactly
// the (row, k-chunk) the MFMA B-fragment read wants at lane L.
// ---------------------------------------------------------------------------
__global__ __launch_bounds__(256) void wconv_kernel(
    const float* __restrict__ W, _Float16* __restrict__ Wh)
{
    const int tid = blockIdx.x * 256 + threadIdx.x;    // 81920 = 1024*80
    const int n   = tid / 80;
    const int c   = tid % 80;                          // k-chunk of 8
    f32x4 a = *(const f32x4*)(W + (size_t)n * 640 + c * 8);
    f32x4 b = *(const f32x4*)(W + (size_t)n * 640 + c * 8 + 4);
    f16x8 h;
#pragma unroll
    for (int j = 0; j < 4; ++j) { h[j] = (_Float16)a[j]; h[4 + j] = (_Float16)b[j]; }
    const int seg = n >> 4;
    const int kc  = c >> 2;
    const int L   = (n & 15) + 16 * (c & 3);
    *(f16x8*)(Wh + (size_t)seg * 10240 + kc * 512 + L * 8) = h;
}

// ---------------------------------------------------------------------------
// Kernel 3: fused tanh + big GEMM.  BM=128, BN=512, BK=32, 512 thr = 8 waves
// (2m x 4n), wave tile 64m x 128n (4x8 frags, 128 AGPR). 1 block/CU.
// B: tiled-gll -> identity LDS (zero conflicts, coalesced global).
// A: chunk-region stride 1040 f16 (2080B ≡ 2 mod 8 quads): zero-conflict
//    write (2q+r distinct) and read (2lk+r distinct) per 8-lane group.
// Per-iter: f/g loads(next) -> gll B(next) -> frag reads(cur) ->
//           MFMA(cur, setprio) -> tanh(next) -> ds_write A(next) -> sync.
// ---------------------------------------------------------------------------
__global__ __launch_bounds__(512, 2) void joint_kernel(
    const float* __restrict__ fg, const _Float16* __restrict__ Wh,
    const float* __restrict__ bias, float* __restrict__ out)
{
    __shared__ _Float16 Ash0[4 * 1040];    // 8320 B
    __shared__ _Float16 Ash1[4 * 1040];
    __shared__ _Float16 Bsh0[512 * 32];    // 32 KB
    __shared__ _Float16 Bsh1[512 * 32];

    const int bid = blockIdx.x;            // 2048
    const int pp  = bid >> 1;              // 1024 m-tiles
    const int mt  = (pp & 7) * 128 + (pp >> 3);   // XCD-chunked (bijective)
    const int nt  = bid & 1;
    const int m0  = mt << 7;
    const int n0s = nt * 32;               // first B segment (16 rows each)

    const int t    = threadIdx.x;
    const int lane = t & 63;
    const int wid  = t >> 6;
    const int wm   = wid & 1;              // m half (64 rows)
    const int wn   = wid >> 1;             // n quarter (128 cols)
    const int lr   = lane & 15;
    const int lk   = lane >> 4;

    // stage-A mapping: 4 threads per row, 8 k each
    const int r  = t >> 2;                 // 0..127
    const int q  = t & 3;
    const int m  = m0 + r;
    const float* grow = fg + (size_t)(2048 + ((m >> 14) << 6) + (m & 63)) * 640;
    const float* frow = fg + (size_t)(m >> 6) * 640;

    // ---- loop-invariant LDS offsets (f16 elems) ----
    int aoff[4];
#pragma unroll
    for (int mf = 0; mf < 4; ++mf)
        aoff[mf] = lk * 1040 + (wm * 64 + mf * 16 + lr) * 8;
    int boff[8];
#pragma unroll
    for (int nf = 0; nf < 8; ++nf)
        boff[nf] = (wn * 8 + nf) * 512 + lane * 8;   // identity: zero conflict
    const int awoff = q * 1040 + r * 8;

    // gll: wave stages 4 segments; lane-l source = tile base + l*8 (1KB cont.)
    const _Float16* gbase = Wh + (size_t)(n0s + wid * 4) * 10240 + lane * 8;
    int gdst[4];
#pragma unroll
    for (int i = 0; i < 4; ++i)
        gdst[i] = (wid * 4 + i) * 512;

    f32x4 acc[4][8];
#pragma unroll
    for (int i = 0; i < 4; ++i)
#pragma unroll
        for (int j = 0; j < 8; ++j) acc[i][j] = (f32x4){0.f, 0.f, 0.f, 0.f};

    // ---- prologue: stage k-range 0 into Ash0/Bsh0 ----
    {
        f32x4 fv0 = *(const f32x4*)(frow + q * 8);
        f32x4 fv1 = *(const f32x4*)(frow + q * 8 + 4);
        f32x4 gv0 = *(const f32x4*)(grow + q * 8);
        f32x4 gv1 = *(const f32x4*)(grow + q * 8 + 4);
#pragma unroll
        for (int i = 0; i < 4; ++i)
            gll16(gbase + (size_t)i * 10240, &Bsh0[gdst[i]]);
        f16x8 h;
#pragma unroll
        for (int j = 0; j < 4; ++j) {
            h[j]     = (_Float16)fast_tanh(fv0[j] + gv0[j]);
            h[4 + j] = (_Float16)fast_tanh(fv1[j] + gv1[j]);
        }
        *(f16x8*)&Ash0[awoff] = h;
        __syncthreads();
    }

#define JITER_FULL(K0, CA, CB, NA, NB)                                         \
    {                                                                          \
        const int kn_ = (K0) + 32;                                             \
        /* f/g loads FIRST: tanh waits at vmcnt(4), glls stay in flight */     \
        f32x4 fv0_ = *(const f32x4*)(frow + kn_ + q * 8);                      \
        f32x4 fv1_ = *(const f32x4*)(frow + kn_ + q * 8 + 4);                  \
        f32x4 gv0_ = *(const f32x4*)(grow + kn_ + q * 8);                      \
        f32x4 gv1_ = *(const f32x4*)(grow + kn_ + q * 8 + 4);                  \
        _Pragma("unroll")                                                      \
        for (int i = 0; i < 4; ++i)                                            \
            gll16(gbase + (size_t)i * 10240 + kn_ * 16, &NB[gdst[i]]);         \
        f16x8 af[4], bf[8];                                                    \
        _Pragma("unroll")                                                      \
        for (int mf = 0; mf < 4; ++mf)                                         \
            af[mf] = *(const f16x8*)&CA[aoff[mf]];                             \
        _Pragma("unroll")                                                      \
        for (int nf = 0; nf < 8; ++nf)                                         \
            bf[nf] = *(const f16x8*)&CB[boff[nf]];                             \
        __builtin_amdgcn_s_setprio(1);                                         \
        _Pragma("unroll")                                                      \
        for (int mf = 0; mf < 4; ++mf)                                         \
            _Pragma("unroll")                                                  \
            for (int nf = 0; nf < 8; ++nf)                                     \
                acc[mf][nf] = __builtin_amdgcn_mfma_f32_16x16x32_f16(          \
                    af[mf], bf[nf], acc[mf][nf], 0, 0, 0);                     \
        __builtin_amdgcn_s_setprio(0);                                         \
        {                                                                      \
            f16x8 h;                                                           \
            _Pragma("unroll")                                                  \
            for (int j = 0; j < 4; ++j) {                                      \
                h[j]     = (_Float16)fast_tanh(fv0_[j] + gv0_[j]);             \
                h[4 + j] = (_Float16)fast_tanh(fv1_[j] + gv1_[j]);             \
            }                                                                  \
            *(f16x8*)&NA[awoff] = h;                                           \
        }                                                                      \
        __syncthreads();                                                       \
    }

#define JITER_LAST(CA, CB)                                                     \
    {                                                                          \
        f16x8 af[4], bf[8];                                                    \
        _Pragma("unroll")                                                      \
        for (int mf = 0; mf < 4; ++mf)                                         \
            af[mf] = *(const f16x8*)&CA[aoff[mf]];                             \
        _Pragma("unroll")                                                      \
        for (int nf = 0; nf < 8; ++nf)                                         \
            bf[nf] = *(const f16x8*)&CB[boff[nf]];                             \
        __builtin_amdgcn_s_setprio(1);                                         \
        _Pragma("unroll")                                                      \
        for (int mf = 0; mf < 4; ++mf)                                         \
            _Pragma("unroll")                                                  \
            for (int nf = 0; nf < 8; ++nf)                                     \
                acc[mf][nf] = __builtin_amdgcn_mfma_f32_16x16x32_f16(          \
                    af[mf], bf[nf], acc[mf][nf], 0, 0, 0);                     \
        __builtin_amdgcn_s_setprio(0);                                         \
    }

    for (int kc = 0; kc < 18; kc += 2) {
        JITER_FULL(kc * 32,      Ash0, Bsh0, Ash1, Bsh1);
        JITER_FULL(kc * 32 + 32, Ash1, Bsh1, Ash0, Bsh0);
    }
    JITER_FULL(576, Ash0, Bsh0, Ash1, Bsh1);   // computes k=576, stages 608
    JITER_LAST(Ash1, Bsh1);                    // computes k=608

#undef JITER_FULL
#undef JITER_LAST

    // ---- epilogue: + bias, store fp32 ----
    float bv[8];
#pragma unroll
    for (int nf = 0; nf < 8; ++nf)
        bv[nf] = bias[nt * 512 + wn * 128 + nf * 16 + lr];

#pragma unroll
    for (int mf = 0; mf < 4; ++mf) {
#pragma unroll
        for (int rr = 0; rr < 4; ++rr) {
            const int row = m0 + wm * 64 + mf * 16 + lk * 4 + rr;
            float* orow = out + (size_t)row * 1024 + nt * 512 + wn * 128;
#pragma unroll
            for (int nf = 0; nf < 8; ++nf)
                orow[nf * 16 + lr] = acc[mf][nf][rr] + bv[nf];
        }
    }
}

// ---------------------------------------------------------------------------
extern "C" void kernel_launch(void* const* d_in, const int* in_sizes, int n_in,
                              void* d_out, int out_size, void* d_ws, size_t ws_size,
                              hipStream_t stream) {
    const float* enc   = (const float*)d_in[0];   // [8,256,512]
    const float* pred  = (const float*)d_in[1];   // [8,64,512]
    const float* Wenc  = (const float*)d_in[2];   // [640,512]
    const float* Wpred = (const float*)d_in[3];   // [640,512]
    const float* Wout  = (const float*)d_in[4];   // [1024,640]
    const float* bout  = (const float*)d_in[5];   // [1024]

    float*     fg = (float*)d_ws;                              // 2560*640 fp32
    _Float16*  Wh = (_Float16*)((char*)d_ws + 2560 * 640 * 4); // tiled 1.25MB

    fg_kernel<<<400, 256, 0, stream>>>(enc, pred, Wenc, Wpred, fg);
    wconv_kernel<<<320, 256, 0, stream>>>(Wout, Wh);
    joint_kernel<<<2048, 512, 0, stream>>>(fg, Wh, bout, (float*)d_out);
}